// Round 3
// baseline (261.513 us; speedup 1.0000x reference)
//
#include <hip/hip_runtime.h>

typedef __attribute__((ext_vector_type(8))) short short8;
typedef __attribute__((ext_vector_type(4))) float f32x4;

__device__ __forceinline__ unsigned short f2bf(float f) {
  unsigned int u = __float_as_uint(f);
  u += 0x7fffu + ((u >> 16) & 1u);   // round-to-nearest-even
  return (unsigned short)(u >> 16);
}

__device__ __forceinline__ short8 load_af(const unsigned short* p) {
  union { uint2 u[2]; short8 v; } r;
  r.u[0] = *(const uint2*)(p);        // k = k0..k0+3
  r.u[1] = *(const uint2*)(p + 16);   // k = k0+16..k0+19
  return r.v;
}

// ---------------------------------------------------------------------------
// prep 1: Weff1 = (truncated 192-mode rDFT basis) @ W1   -> dw1 [1024][256] fp32
// DW1[n][j] = sum_m cos(2pi m n/1024) W1[2m][j] - sin(2pi m n/1024) W1[2m+1][j]
// ---------------------------------------------------------------------------
__global__ void prep_dw1_kernel(const float* __restrict__ W1, float* __restrict__ dw1) {
  __shared__ float cs[1536];
  __shared__ float sn[1536];
  const int t = threadIdx.x;
  const int n0 = blockIdx.x * 8;
  for (int i = t; i < 1536; i += 256) {
    int r = i / 192, m = i - r * 192;
    int ph = ((n0 + r) * m) & 1023;              // exact integer phase reduction
    float ang = (float)ph * 6.135923151542565e-3f; // 2*pi/1024
    float s, c;
    __sincosf(ang, &s, &c);
    cs[i] = c;
    sn[i] = s;
  }
  __syncthreads();
  float acc[8] = {0.f, 0.f, 0.f, 0.f, 0.f, 0.f, 0.f, 0.f};
  for (int m = 0; m < 192; ++m) {
    float wre = W1[(2 * m) * 256 + t];
    float wim = W1[(2 * m + 1) * 256 + t];
#pragma unroll
    for (int r = 0; r < 8; ++r) {
      acc[r] += cs[r * 192 + m] * wre - sn[r * 192 + m] * wim;
    }
  }
#pragma unroll
  for (int r = 0; r < 8; ++r) dw1[(size_t)(n0 + r) * 256 + t] = acc[r];
}

// ---------------------------------------------------------------------------
// prep 2: pre-swizzle W matrices (bf16) into per-lane MFMA B-fragment order.
// Fragment for (ntile, kk): lane l, elems e=0..7:
//   k = kk*32 + 4*(l>>4) + (e&3) + 16*(e>>2),  n = ntile*16 + (l&15)
// stored as 16B per lane, lane-major (1 KiB per 16x32 tile).
// tile_id = ntile*KS + kk.   L1: 16x32=512 tiles (src dw1), L2: 8x8=64, L3: 2x4=8.
// ---------------------------------------------------------------------------
__global__ void prep_swz_kernel(const float* __restrict__ W2, const float* __restrict__ W3,
                                const float* __restrict__ dw1,
                                unsigned short* __restrict__ fL1,
                                unsigned short* __restrict__ fL2,
                                unsigned short* __restrict__ fL3) {
  int g = blockIdx.x * 256 + threadIdx.x;   // 146*256 = 37376 = 584 tiles * 64 lanes
  int tile = g >> 6, lane = g & 63;
  const float* src;
  unsigned short* dst;
  int ldN, KS, tl;
  if (tile < 512)      { tl = tile;       src = dw1; dst = fL1; ldN = 256; KS = 32; }
  else if (tile < 576) { tl = tile - 512; src = W2;  dst = fL2; ldN = 128; KS = 8; }
  else                 { tl = tile - 576; src = W3;  dst = fL3; ldN = 32;  KS = 4; }
  int nt = tl / KS, kk = tl - nt * KS;
  int k0 = kk * 32 + ((lane >> 4) << 2);
  int col = nt * 16 + (lane & 15);
  unsigned int d[4];
#pragma unroll
  for (int dw = 0; dw < 4; ++dw) {
    int e0 = dw * 2, e1 = e0 + 1;
    int ka = k0 + (e0 & 3) + ((e0 >> 2) << 4);
    int kb = k0 + (e1 & 3) + ((e1 >> 2) << 4);
    d[dw] = (unsigned int)f2bf(src[ka * ldN + col]) |
            ((unsigned int)f2bf(src[kb * ldN + col]) << 16);
  }
  uint4 v; v.x = d[0]; v.y = d[1]; v.z = d[2]; v.w = d[3];
  *(uint4*)(dst + ((size_t)tl * 64 + lane) * 8) = v;
}

// ---------------------------------------------------------------------------
// main fused MLP: h1 = leaky(x@DW1+b1); h2 = leaky(h1@W2+b2); out = h2@W3+b3
// block = 256 thr (4 waves), BM = 64 rows. Wave w: L1 cols [64w,64w+64),
// L2 cols [32w,32w+32), L3 rowtile w x all 32 cols.
// ---------------------------------------------------------------------------
#define XS_S 136   // 128 + 8 pad (ushort stride)
#define H1_S 264   // 256 + 8
#define H2_S 136   // 128 + 8

__global__ __launch_bounds__(256, 2) void mlp_kernel(
    const float* __restrict__ x,
    const float* __restrict__ b1, const float* __restrict__ b2,
    const float* __restrict__ b3,
    const unsigned short* __restrict__ fL1, const unsigned short* __restrict__ fL2,
    const unsigned short* __restrict__ fL3, float* __restrict__ out) {
  __shared__ unsigned short xs[64 * XS_S];
  __shared__ unsigned short hs1[64 * H1_S];
  __shared__ unsigned short hs2[64 * H2_S];
  const int t = threadIdx.x;
  const int lane = t & 63;
  const int wid = t >> 6;
  const int rlo = lane & 15;
  const int g4 = (lane >> 4) << 2;
  const size_t row0 = (size_t)blockIdx.x * 64;

  f32x4 acc[4][4] = {};

  for (int kc = 0; kc < 8; ++kc) {
    // ---- stage 64x128 fp32 -> bf16 into LDS (coalesced float4 loads)
#pragma unroll
    for (int i = 0; i < 8; ++i) {
      int idx = i * 256 + t;
      int row = idx >> 5, cg = idx & 31;
      const float4* p = (const float4*)(x + (row0 + row) * 1024 + kc * 128 + cg * 4);
      float4 v = *p;
      uint2 w;
      w.x = (unsigned int)f2bf(v.x) | ((unsigned int)f2bf(v.y) << 16);
      w.y = (unsigned int)f2bf(v.z) | ((unsigned int)f2bf(v.w) << 16);
      *(uint2*)(xs + row * XS_S + cg * 4) = w;
    }
    __syncthreads();
    // ---- 4 K-steps of 32
#pragma unroll
    for (int ks = 0; ks < 4; ++ks) {
      short8 af[4];
#pragma unroll
      for (int m = 0; m < 4; ++m)
        af[m] = load_af(xs + (m * 16 + rlo) * XS_S + ks * 32 + g4);
      short8 bfr[4];
#pragma unroll
      for (int c = 0; c < 4; ++c)
        bfr[c] = *(const short8*)(fL1 +
                 (((size_t)(wid * 4 + c) * 32 + kc * 4 + ks) * 64 + lane) * 8);
#pragma unroll
      for (int m = 0; m < 4; ++m)
#pragma unroll
        for (int c = 0; c < 4; ++c)
          acc[m][c] = __builtin_amdgcn_mfma_f32_16x16x32_bf16(af[m], bfr[c], acc[m][c], 0, 0, 0);
    }
    __syncthreads();
  }

  // ---- L1 epilogue: bias + leaky + bf16 -> hs1
  {
    float bv[4];
#pragma unroll
    for (int c = 0; c < 4; ++c) bv[c] = b1[wid * 64 + c * 16 + rlo];
#pragma unroll
    for (int m = 0; m < 4; ++m)
#pragma unroll
      for (int c = 0; c < 4; ++c)
#pragma unroll
        for (int r = 0; r < 4; ++r) {
          float v = acc[m][c][r] + bv[c];
          v = fmaxf(v, 0.01f * v);
          hs1[(m * 16 + g4 + r) * H1_S + wid * 64 + c * 16 + rlo] = f2bf(v);
        }
  }
  __syncthreads();

  // ---- L2: 64 rows x 32 cols per wave, K = 256
  f32x4 a2[4][2] = {};
#pragma unroll
  for (int ks = 0; ks < 8; ++ks) {
    short8 af[4];
#pragma unroll
    for (int m = 0; m < 4; ++m)
      af[m] = load_af(hs1 + (m * 16 + rlo) * H1_S + ks * 32 + g4);
    short8 bfr[2];
#pragma unroll
    for (int c = 0; c < 2; ++c)
      bfr[c] = *(const short8*)(fL2 + (((size_t)(wid * 2 + c) * 8 + ks) * 64 + lane) * 8);
#pragma unroll
    for (int m = 0; m < 4; ++m)
#pragma unroll
      for (int c = 0; c < 2; ++c)
        a2[m][c] = __builtin_amdgcn_mfma_f32_16x16x32_bf16(af[m], bfr[c], a2[m][c], 0, 0, 0);
  }
  {
    float bv[2];
#pragma unroll
    for (int c = 0; c < 2; ++c) bv[c] = b2[wid * 32 + c * 16 + rlo];
#pragma unroll
    for (int m = 0; m < 4; ++m)
#pragma unroll
      for (int c = 0; c < 2; ++c)
#pragma unroll
        for (int r = 0; r < 4; ++r) {
          float v = a2[m][c][r] + bv[c];
          v = fmaxf(v, 0.01f * v);
          hs2[(m * 16 + g4 + r) * H2_S + wid * 32 + c * 16 + rlo] = f2bf(v);
        }
  }
  __syncthreads();

  // ---- L3: rowtile = wid (16 rows) x 32 cols, K = 128, no activation
  f32x4 a3[2] = {};
#pragma unroll
  for (int ks = 0; ks < 4; ++ks) {
    short8 af = load_af(hs2 + (wid * 16 + rlo) * H2_S + ks * 32 + g4);
#pragma unroll
    for (int c = 0; c < 2; ++c) {
      short8 bfr = *(const short8*)(fL3 + (((size_t)c * 4 + ks) * 64 + lane) * 8);
      a3[c] = __builtin_amdgcn_mfma_f32_16x16x32_bf16(af, bfr, a3[c], 0, 0, 0);
    }
  }
  {
    float bv[2];
    bv[0] = b3[rlo];
    bv[1] = b3[16 + rlo];
#pragma unroll
    for (int c = 0; c < 2; ++c)
#pragma unroll
      for (int r = 0; r < 4; ++r)
        out[(row0 + wid * 16 + g4 + r) * 32 + c * 16 + rlo] = a3[c][r] + bv[c];
  }
}

// ---------------------------------------------------------------------------
extern "C" void kernel_launch(void* const* d_in, const int* in_sizes, int n_in,
                              void* d_out, int out_size, void* d_ws, size_t ws_size,
                              hipStream_t stream) {
  const float* x  = (const float*)d_in[0];
  const float* W1 = (const float*)d_in[1];
  const float* b1 = (const float*)d_in[2];
  const float* W2 = (const float*)d_in[3];
  const float* b2 = (const float*)d_in[4];
  const float* W3 = (const float*)d_in[5];
  const float* b3 = (const float*)d_in[6];
  float* out = (float*)d_out;

  char* ws = (char*)d_ws;
  float* dw1          = (float*)ws;                         // 1024*256*4     = 1048576 B
  unsigned short* fL1 = (unsigned short*)(ws + 1048576);    // 512 tiles*1KiB =  524288 B
  unsigned short* fL2 = (unsigned short*)(ws + 1572864);    //  64 tiles      =   65536 B
  unsigned short* fL3 = (unsigned short*)(ws + 1638400);    //   8 tiles      =    8192 B

  hipLaunchKernelGGL(prep_dw1_kernel, dim3(128), dim3(256), 0, stream, W1, dw1);
  hipLaunchKernelGGL(prep_swz_kernel, dim3(146), dim3(256), 0, stream, W2, W3, dw1,
                     fL1, fL2, fL3);
  hipLaunchKernelGGL(mlp_kernel, dim3(512), dim3(256), 0, stream,
                     x, b1, b2, b3, fL1, fL2, fL3, out);
}